// Round 1
// 251.136 us; speedup vs baseline: 1.0246x; 1.0246x over previous
//
#include <hip/hip_runtime.h>

typedef _Float16 f16;
typedef __attribute__((ext_vector_type(4))) _Float16 f16x4;
typedef __attribute__((ext_vector_type(8))) _Float16 f16x8;
typedef __attribute__((ext_vector_type(4))) float f32x4;
typedef __attribute__((ext_vector_type(16))) float f32x16;
typedef unsigned int u32;

#define BB 32
#define LL 1024
#define DD 256

// async global->LDS, 16B per lane, dst = ldsbase + lane*16 (wave-uniform base)
__device__ __forceinline__ void async_copy16(const f16* g, f16* l) {
  __builtin_amdgcn_global_load_lds(
      (const __attribute__((address_space(1))) u32*)(const void*)g,
      (__attribute__((address_space(3))) u32*)(void*)l, 16, 0, 0);
}

// pack two f32 -> f16x2 in a u32 (v_cvt_pkrtz_f16_f32)
__device__ __forceinline__ u32 pack_pkrtz(float a, float b) {
  auto pk = __builtin_amdgcn_cvt_pkrtz(a, b);  // __fp16 ext_vector(2)
  u32 w;
  __builtin_memcpy(&w, &pk, 4);
  return w;
}

// ---------------------------------------------------------------------------
// Transpose + fp32->fp16 (used only for the tiny W^T).
// ---------------------------------------------------------------------------
__global__ __launch_bounds__(256) void transpose_to_f16(
    const float* __restrict__ X0, f16* __restrict__ Y0,
    const float* __restrict__ X1, f16* __restrict__ Y1,
    int L, int D, int nbPerInput) {
  __shared__ float T[64][68];
  const int tid = threadIdx.x;
  int bz = blockIdx.z;
  const float* X = X0;
  f16* Y = Y0;
  int b = bz;
  if (bz >= nbPerInput) { X = X1; Y = Y1; b = bz - nbPerInput; }
  const int l0 = blockIdx.x * 64, d0 = blockIdx.y * 64;
  const size_t baseX = (size_t)b * L * D;
#pragma unroll
  for (int pass = 0; pass < 4; ++pass) {
    int r = (tid >> 4) + pass * 16;
    int c = (tid & 15) * 4;
    float4 v = *(const float4*)&X[baseX + (size_t)(l0 + r) * D + d0 + c];
    *(float4*)&T[r][c] = v;
  }
  __syncthreads();
  const size_t baseY = (size_t)b * D * L;
#pragma unroll
  for (int pass = 0; pass < 2; ++pass) {
    int dr = (tid >> 3) + pass * 32;
    int lc = (tid & 7) * 8;
    f16x8 o;
#pragma unroll
    for (int j = 0; j < 8; ++j) o[j] = (f16)T[lc + j][dr];
    *(f16x8*)&Y[baseY + (size_t)(d0 + dr) * L + l0 + lc] = o;
  }
}

// ---------------------------------------------------------------------------
// Projection: F = tanh(A @ W)  (f16 out)  +  fused X^T f16 write.
// Block: 256 thr = 4 waves, tile 64m x 256n (full N per block -> A read ONCE).
// A tile staged fully in LDS (64x256 f16), A-frags hoisted to regs; the 4
// n-chunks loop internally, restaging only the L2-hot 64x256 W panel.
// ---------------------------------------------------------------------------
__global__ __launch_bounds__(256, 2) void proj_mfma(
    const float* __restrict__ Pin, const float* __restrict__ Hin,
    const f16* __restrict__ Wt, f16* __restrict__ Fp, f16* __restrict__ Fh,
    f16* __restrict__ Vtp, f16* __restrict__ Vth) {
  __shared__ f16 As[64][264];   // full 64m x 256k A tile, +8 pad
  __shared__ f16 Wts[64][264];  // one 64n x 256k W chunk, +8 pad
  const int tid = threadIdx.x;
  const int wv = tid >> 6, lane = tid & 63, quad = lane >> 4, l16 = lane & 15;
  const float* A = blockIdx.z ? Hin : Pin;
  f16* F = blockIdx.z ? Fh : Fp;
  f16* VtO = blockIdx.z ? Vth : Vtp;
  const int m0 = blockIdx.x * 64;

  // stage full A tile (64 x 256) fp32 -> f16, once
  {
    const int ar = tid >> 2, aq = tid & 3;
    const float* arow = A + (size_t)(m0 + ar) * 256 + aq * 64;
    f16* drow = &As[ar][aq * 64];
#pragma unroll
    for (int i = 0; i < 16; ++i) {
      float4 v = *(const float4*)&arow[i * 4];
      f16x4 bv;
      bv[0] = (f16)v.x; bv[1] = (f16)v.y; bv[2] = (f16)v.z; bv[3] = (f16)v.w;
      *(f16x4*)&drow[i * 4] = bv;
    }
  }
  __syncthreads();

  // hoist all 8 A fragments to regs (reused across all 4 n-chunks)
  f16x8 af[8];
#pragma unroll
  for (int kc = 0; kc < 4; ++kc)
#pragma unroll
    for (int s = 0; s < 2; ++s)
      af[kc * 2 + s] =
          *(const f16x8*)&As[wv * 16 + l16][kc * 64 + s * 32 + quad * 8];

  // fused X^T emit: all 256 d-rows for this 64-l range, from staged A
  {
    const int dd = tid & 63, lg = tid >> 6;
    const int bI = m0 >> 10, l_base = m0 & 1023;
#pragma unroll
    for (int kc = 0; kc < 4; ++kc) {
      f16* vrow =
          VtO + (size_t)bI * DD * LL + (size_t)(kc * 64 + dd) * LL + l_base;
#pragma unroll
      for (int part = 0; part < 2; ++part) {
        int lo = lg * 16 + part * 8;
        f16x8 ov;
#pragma unroll
        for (int j = 0; j < 8; ++j) ov[j] = As[lo + j][kc * 64 + dd];
        *(f16x8*)&vrow[lo] = ov;
      }
    }
  }

  for (int nc = 0; nc < 4; ++nc) {
    __syncthreads();  // previous chunk's Wts reads complete
#pragma unroll
    for (int pass = 0; pass < 8; ++pass) {
      int row = (tid >> 5) + pass * 8;
      int chunk = tid & 31;
      *(f16x8*)&Wts[row][chunk * 8] =
          *(const f16x8*)&Wt[(size_t)(nc * 64 + row) * 256 + chunk * 8];
    }
    __syncthreads();
    f32x4 acc[4] = {};
#pragma unroll
    for (int kc = 0; kc < 4; ++kc)
#pragma unroll
      for (int s = 0; s < 2; ++s) {
#pragma unroll
        for (int t = 0; t < 4; ++t) {
          f16x8 wf =
              *(const f16x8*)&Wts[t * 16 + l16][kc * 64 + s * 32 + quad * 8];
          acc[t] = __builtin_amdgcn_mfma_f32_16x16x32_f16(af[kc * 2 + s], wf,
                                                          acc[t], 0, 0, 0);
        }
      }
#pragma unroll
    for (int t = 0; t < 4; ++t)
#pragma unroll
      for (int r = 0; r < 4; ++r) {
        float x = acc[t][r];
        float e = __expf(2.f * x);
        float th = 1.f - 2.f / (e + 1.f);
        F[(size_t)(m0 + wv * 16 + quad * 4 + r) * 256 + nc * 64 + t * 16 +
          l16] = (f16)th;
      }
  }
}

// ---------------------------------------------------------------------------
// Flash alignment, 32x32x16 MFMA, transposed formulation:
//   S^T = K Q^T  (A=K frags from LDS, B=Q frags in regs)
//   O^T = V^T P^T (A=V^T frags from LDS, B=P^T built by cross-half shuffle)
// NEW: double-buffered LDS (64 KB) with next-tile prefetch issued before
// compute (T3 2-phase: one syncthreads/tile, load latency hidden under MFMA);
// defer-max rescale (T13, THR=8); XCD-locality blockIdx swizzle (T1).
// ---------------------------------------------------------------------------
__global__ __launch_bounds__(256, 2) void flash_mfma(
    const f16* __restrict__ Fpm, const f16* __restrict__ Fhm,
    const f16* __restrict__ Vth, const f16* __restrict__ Vtp,
    float* __restrict__ Out) {
  __shared__ f16 Kf[2][16][512];  // K frag s: lane -> K[q0+l32][s*16+half*8..+8]
  __shared__ f16 Vf[2][16][512];  // V frag v=t*2+h: lane -> V^T[t*32+l32][q0+h*16+half*8..+8]

  const int tid = threadIdx.x;
  const int wv = tid >> 6, lane = tid & 63;
  const int l32 = lane & 31, half = lane >> 5;

  const f16* Fq = Fpm;
  const f16* Fk = Fhm;
  const f16* Vt = Vth;
  float* O = Out;
  if (blockIdx.y) { Fq = Fhm; Fk = Fpm; Vt = Vtp; O = Out + (size_t)BB * LL * DD; }

  // XCD-locality swizzle (bijective): x = [b1 b0 | t2 t1 t0 | b4 b3 b2]
  // -> the 8 p-tiles of one batch share x%8, i.e. one XCD residue class.
  const int x = blockIdx.x;
  const int b = ((x & 7) << 2) | (x >> 6);
  const int p0 = ((x >> 3) & 7) * 128 + wv * 32;
  const int p = p0 + l32;  // this lane's p-column

  const f16* Fq_b = Fq + (size_t)b * LL * DD;
  const f16* Fk_b = Fk + (size_t)b * LL * DD;
  const f16* Vt_b = Vt + (size_t)b * DD * LL;

  // Q fragments (B-operand): n=p=l32, k=half*8+j, 16 k-steps of 16
  f16x8 qf[16];
  {
    const f16* qrow = Fq_b + (size_t)p * DD + half * 8;
#pragma unroll
    for (int s = 0; s < 16; ++s) qf[s] = *(const f16x8*)&qrow[s * 16];
  }

  float m_run = -1e30f, l_run = 0.f;
  f32x16 o[8];
#pragma unroll
  for (int t = 0; t < 8; ++t) o[t] = (f32x16)(0.f);

  auto stage = [&](int buf, int q0) {
#pragma unroll
    for (int i = 0; i < 4; ++i) {
      int s = wv * 4 + i;
      async_copy16(Fk_b + (size_t)(q0 + l32) * DD + s * 16 + half * 8,
                   &Kf[buf][s][0]);
    }
#pragma unroll
    for (int i = 0; i < 4; ++i) {
      int v = wv * 4 + i;
      int t = v >> 1, h = v & 1;
      async_copy16(Vt_b + (size_t)(t * 32 + l32) * LL + q0 + h * 16 + half * 8,
                   &Vf[buf][v][0]);
    }
  };

  stage(0, 0);
  __syncthreads();  // prologue tile landed (vmcnt drained at barrier)

  int cur = 0;
  for (int it = 0; it < LL / 32; ++it) {
    // issue next tile's DMA first -- lands during compute below
    if (it + 1 < LL / 32) stage(cur ^ 1, (it + 1) * 32);

    // S^T[q][p]: A = K frag (m=q), B = Q frag (n=p)
    f32x16 S = (f32x16)(0.f);
#pragma unroll
    for (int s = 0; s < 16; ++s) {
      f16x8 kf = *(const f16x8*)&Kf[cur][s][lane * 8];  // conflict-free b128
      S = __builtin_amdgcn_mfma_f32_32x32x16_f16(kf, qf[s], S, 0, 0, 0);
    }

    // in-lane softmax: lane holds 16 q-values of its p; merge with other half
    float mt = S[0];
#pragma unroll
    for (int r = 1; r < 16; ++r) mt = fmaxf(mt, S[r]);
    mt = fmaxf(mt, __shfl_xor(mt, 32, 64));

    // defer-max: skip O-rescale while max growth <= 8 (P bounded by e^8,
    // safely inside f16 range); wave-uniform branch via __all.
    const bool keep = __all((int)(mt - m_run <= 8.0f)) != 0;
    const float mn = keep ? m_run : fmaxf(m_run, mt);
    float pe[16];
    float ts = 0.f;
#pragma unroll
    for (int r = 0; r < 16; ++r) {
      pe[r] = __expf(S[r] - mn);
      ts += pe[r];
    }
    ts += __shfl_xor(ts, 32, 64);
    if (!keep) {
      const float alpha = __expf(m_run - mn);
      l_run *= alpha;
      m_run = mn;
#pragma unroll
      for (int t = 0; t < 8; ++t)
#pragma unroll
        for (int r = 0; r < 16; ++r) o[t][r] *= alpha;
    }
    l_run += ts;

    // build P^T B-frags: pack f16 pairs, exchange cross-half (4 shfl)
    u32 pw[8];
#pragma unroll
    for (int i = 0; i < 8; ++i) pw[i] = pack_pkrtz(pe[2 * i], pe[2 * i + 1]);
    u32 rc[4];
    {
      u32 s0 = half ? pw[0] : pw[2];
      u32 s1 = half ? pw[1] : pw[3];
      u32 s2 = half ? pw[4] : pw[6];
      u32 s3 = half ? pw[5] : pw[7];
      rc[0] = (u32)__shfl_xor((int)s0, 32, 64);
      rc[1] = (u32)__shfl_xor((int)s1, 32, 64);
      rc[2] = (u32)__shfl_xor((int)s2, 32, 64);
      rc[3] = (u32)__shfl_xor((int)s3, 32, 64);
    }
    f16x8 pf[2];
#pragma unroll
    for (int h = 0; h < 2; ++h) {
      u32 tmp[4];
      tmp[0] = half ? rc[2 * h] : pw[4 * h];
      tmp[1] = half ? rc[2 * h + 1] : pw[4 * h + 1];
      tmp[2] = half ? pw[4 * h + 2] : rc[2 * h];
      tmp[3] = half ? pw[4 * h + 3] : rc[2 * h + 1];
      __builtin_memcpy(&pf[h], tmp, 16);
    }

    // O^T += V^T P^T
#pragma unroll
    for (int t = 0; t < 8; ++t) {
      f16x8 v0 = *(const f16x8*)&Vf[cur][t * 2][lane * 8];
      o[t] = __builtin_amdgcn_mfma_f32_32x32x16_f16(v0, pf[0], o[t], 0, 0, 0);
      f16x8 v1 = *(const f16x8*)&Vf[cur][t * 2 + 1][lane * 8];
      o[t] = __builtin_amdgcn_mfma_f32_32x32x16_f16(v1, pf[1], o[t], 0, 0, 0);
    }

    __syncthreads();  // drains this tile's prefetch DMA + all LDS reads
    cur ^= 1;
  }

  // epilogue: C row = (r&3) + 8*(r>>2) + 4*half; col = p.  Pack 4 consecutive d.
  const float inv = 1.f / l_run;
  float* orow = O + ((size_t)b * LL + p) * DD;
#pragma unroll
  for (int t = 0; t < 8; ++t) {
#pragma unroll
    for (int g = 0; g < 4; ++g) {
      f32x4 v;
      v[0] = o[t][4 * g + 0] * inv;
      v[1] = o[t][4 * g + 1] * inv;
      v[2] = o[t][4 * g + 2] * inv;
      v[3] = o[t][4 * g + 3] * inv;
      *(f32x4*)&orow[t * 32 + 8 * g + 4 * half] = v;
    }
  }
}

// ---------------------------------------------------------------------------
extern "C" void kernel_launch(void* const* d_in, const int* in_sizes, int n_in,
                              void* d_out, int out_size, void* d_ws,
                              size_t ws_size, hipStream_t stream) {
  const float* premises = (const float*)d_in[0];    // [32,1024,256] fp32
  const float* hypotheses = (const float*)d_in[1];  // [32,1024,256] fp32
  const float* W = (const float*)d_in[2];           // [256,256] fp32
  float* out = (float*)d_out;

  const size_t MF = (size_t)BB * LL * DD;
  f16* Fp = (f16*)d_ws;   // 16 MiB each; ws = 64 MiB exactly
  f16* Fh = Fp + MF;
  f16* Vth = Fh + MF;     // hypotheses^T [B][D][L] f16
  f16* Vtp = Vth + MF;    // premises^T   [B][D][L] f16
  // Wt (131 KB) stashed in d_out tail: used only by proj, overwritten by flash
  f16* Wt = (f16*)((char*)d_out + (size_t)out_size * 4 - 256 * 256 * 2);

  // W^T -> f16
  transpose_to_f16<<<dim3(4, 4, 1), 256, 0, stream>>>(W, Wt, W, Wt, 256, 256, 1);
  // F = tanh(X @ W) f16 + fused X^T f16 emit; full-N per block (A read once)
  proj_mfma<<<dim3(512, 1, 2), 256, 0, stream>>>(premises, hypotheses, Wt, Fp,
                                                 Fh, Vtp, Vth);
  // betas (y=0) and alphas (y=1): 256 blocks/direction, 2 blocks/CU exactly
  flash_mfma<<<dim3(256, 2), 256, 0, stream>>>(Fp, Fh, Vth, Vtp, out);
}

// Round 2
// 227.146 us; speedup vs baseline: 1.1328x; 1.1056x over previous
//
#include <hip/hip_runtime.h>

typedef _Float16 f16;
typedef __attribute__((ext_vector_type(4))) _Float16 f16x4;
typedef __attribute__((ext_vector_type(8))) _Float16 f16x8;
typedef __attribute__((ext_vector_type(4))) float f32x4;
typedef __attribute__((ext_vector_type(16))) float f32x16;
typedef unsigned int u32;

#define BB 32
#define LL 1024
#define DD 256

#define VMCNT(N) asm volatile("s_waitcnt vmcnt(" #N ")" ::: "memory")
#define LGKMCNT0 asm volatile("s_waitcnt lgkmcnt(0)" ::: "memory")

// async global->LDS, 16B per lane, dst = ldsbase + lane*16 (wave-uniform base)
__device__ __forceinline__ void async_copy16(const f16* g, f16* l) {
  __builtin_amdgcn_global_load_lds(
      (const __attribute__((address_space(1))) u32*)(const void*)g,
      (__attribute__((address_space(3))) u32*)(void*)l, 16, 0, 0);
}

// pack two f32 -> f16x2 in a u32 (v_cvt_pkrtz_f16_f32)
__device__ __forceinline__ u32 pack_pkrtz(float a, float b) {
  auto pk = __builtin_amdgcn_cvt_pkrtz(a, b);  // __fp16 ext_vector(2)
  u32 w;
  __builtin_memcpy(&w, &pk, 4);
  return w;
}

// ---------------------------------------------------------------------------
// Transpose + fp32->fp16 (used only for the tiny W^T).
// ---------------------------------------------------------------------------
__global__ __launch_bounds__(256) void transpose_to_f16(
    const float* __restrict__ X0, f16* __restrict__ Y0,
    const float* __restrict__ X1, f16* __restrict__ Y1,
    int L, int D, int nbPerInput) {
  __shared__ float T[64][68];
  const int tid = threadIdx.x;
  int bz = blockIdx.z;
  const float* X = X0;
  f16* Y = Y0;
  int b = bz;
  if (bz >= nbPerInput) { X = X1; Y = Y1; b = bz - nbPerInput; }
  const int l0 = blockIdx.x * 64, d0 = blockIdx.y * 64;
  const size_t baseX = (size_t)b * L * D;
#pragma unroll
  for (int pass = 0; pass < 4; ++pass) {
    int r = (tid >> 4) + pass * 16;
    int c = (tid & 15) * 4;
    float4 v = *(const float4*)&X[baseX + (size_t)(l0 + r) * D + d0 + c];
    *(float4*)&T[r][c] = v;
  }
  __syncthreads();
  const size_t baseY = (size_t)b * D * L;
#pragma unroll
  for (int pass = 0; pass < 2; ++pass) {
    int dr = (tid >> 3) + pass * 32;
    int lc = (tid & 7) * 8;
    f16x8 o;
#pragma unroll
    for (int j = 0; j < 8; ++j) o[j] = (f16)T[lc + j][dr];
    *(f16x8*)&Y[baseY + (size_t)(d0 + dr) * L + l0 + lc] = o;
  }
}

// ---------------------------------------------------------------------------
// Projection: F = tanh(A @ W) (f16) + fused X^T f16 emit.
// Block: 256 thr = 4 waves (2m x 2n), tile 64m x 256n, MFMA 32x32x16:
// 2x FLOP per LDS byte vs 16x16x32; pad 258 (row stride 129 dw == 1 mod 32
// -> 2-way/free bank pattern); A-frags hoisted (reused across all 4 nc);
// coalesced A loads (16 lanes x 16B row-contiguous) and F stores
// (2 rows x 64B full lines per instr).
// ---------------------------------------------------------------------------
__global__ __launch_bounds__(256, 2) void proj_mfma(
    const float* __restrict__ Pin, const float* __restrict__ Hin,
    const f16* __restrict__ Wt, f16* __restrict__ Fp, f16* __restrict__ Fh,
    f16* __restrict__ Vtp, f16* __restrict__ Vth) {
  __shared__ f16 As[64][258];
  __shared__ f16 Wts[64][258];
  const int tid = threadIdx.x;
  const int wv = tid >> 6, lane = tid & 63;
  const int l32 = lane & 31, half = lane >> 5;
  const int wm = wv >> 1, wn = wv & 1;
  const float* A = blockIdx.z ? Hin : Pin;
  f16* F = blockIdx.z ? Fh : Fp;
  f16* VtO = blockIdx.z ? Vth : Vtp;
  const int m0 = blockIdx.x * 64;

  // stage full A tile (64 x 256) fp32 -> f16, fully coalesced rows
  {
    const int r = tid >> 4;          // 0..15
    const int c4 = (tid & 15) * 4;   // 0..60
#pragma unroll
    for (int p = 0; p < 4; ++p)
#pragma unroll
      for (int ch = 0; ch < 4; ++ch) {
        float4 v =
            *(const float4*)&A[(size_t)(m0 + r + p * 16) * 256 + ch * 64 + c4];
        f16x4 h4;
        h4[0] = (f16)v.x; h4[1] = (f16)v.y; h4[2] = (f16)v.z; h4[3] = (f16)v.w;
        *(f16x4*)&As[r + p * 16][ch * 64 + c4] = h4;
      }
  }
  __syncthreads();

  // hoist all 16 A-frags (32x32x16: m=l32, k=half*8+j) -- reused for all nc
  f16x8 af[16];
#pragma unroll
  for (int ks = 0; ks < 16; ++ks)
    af[ks] = *(const f16x8*)&As[wm * 32 + l32][ks * 16 + half * 8];

  // fused X^T emit from staged A (column reads are broadcast-pair, no conflict)
  {
    const int dd = tid & 63, lg = tid >> 6;
    const int bI = m0 >> 10, l_base = m0 & 1023;
#pragma unroll
    for (int kc = 0; kc < 4; ++kc) {
      f16* vrow =
          VtO + (size_t)bI * DD * LL + (size_t)(kc * 64 + dd) * LL + l_base;
#pragma unroll
      for (int part = 0; part < 2; ++part) {
        int lo = lg * 16 + part * 8;
        f16x8 ov;
#pragma unroll
        for (int j = 0; j < 8; ++j) ov[j] = As[lo + j][kc * 64 + dd];
        *(f16x8*)&vrow[lo] = ov;
      }
    }
  }

  for (int nc = 0; nc < 4; ++nc) {
    __syncthreads();  // previous chunk's Wts reads complete
#pragma unroll
    for (int pass = 0; pass < 8; ++pass) {
      int row = (tid >> 5) + pass * 8;
      int chunk = tid & 31;
      *(f16x8*)&Wts[row][chunk * 8] =
          *(const f16x8*)&Wt[(size_t)(nc * 64 + row) * 256 + chunk * 8];
    }
    __syncthreads();
    f32x16 acc = (f32x16)(0.f);
#pragma unroll
    for (int ks = 0; ks < 16; ++ks) {
      f16x8 wf = *(const f16x8*)&Wts[wn * 32 + l32][ks * 16 + half * 8];
      acc = __builtin_amdgcn_mfma_f32_32x32x16_f16(af[ks], wf, acc, 0, 0, 0);
    }
    // C: col = wn*32 + l32 (n), row = wm*32 + (r&3)+8*(r>>2)+4*half (m)
    // store: per r, lanes cover 2 rows x 64B contiguous f16 -> full lines
#pragma unroll
    for (int r = 0; r < 16; ++r) {
      float x = acc[r];
      float e = __expf(2.f * x);
      float th = 1.f - 2.f / (e + 1.f);
      F[(size_t)(m0 + wm * 32 + (r & 3) + 8 * (r >> 2) + 4 * half) * 256 +
        nc * 64 + wn * 32 + l32] = (f16)th;
    }
  }
}

// ---------------------------------------------------------------------------
// Flash alignment, 32x32x16 MFMA, transposed formulation:
//   S^T = K Q^T  (A=K frags from LDS, B=Q frags in regs)
//   O^T = V^T P^T (A=V^T frags from LDS, B=P^T built by cross-half shuffle)
// NEW: counted-vmcnt pipeline (T3/T4): stage(next) -> vmcnt(8) -> s_barrier ->
// compute -> s_barrier. Prefetch stays in flight across barriers (never
// drained to 0 in the loop). setprio(1) around MFMA clusters (T5).
// LDS-bounce epilogue: 32x32 chunks transposed through per-wave LDS tile
// (stride 36: bank-balanced both sides) -> 8 rows x 128B contiguous stores.
// ---------------------------------------------------------------------------
__global__ __launch_bounds__(256, 2) void flash_mfma(
    const f16* __restrict__ Fpm, const f16* __restrict__ Fhm,
    const f16* __restrict__ Vth, const f16* __restrict__ Vtp,
    float* __restrict__ Out) {
  __shared__ f16 Kf[2][16][512];  // K frag s: lane -> K[q0+l32][s*16+half*8..+8]
  __shared__ f16 Vf[2][16][512];  // V frag v=t*2+h: lane -> V^T[t*32+l32][q0+h*16+half*8..+8]

  const int tid = threadIdx.x;
  const int wv = tid >> 6, lane = tid & 63;
  const int l32 = lane & 31, half = lane >> 5;

  const f16* Fq = Fpm;
  const f16* Fk = Fhm;
  const f16* Vt = Vth;
  float* O = Out;
  if (blockIdx.y) { Fq = Fhm; Fk = Fpm; Vt = Vtp; O = Out + (size_t)BB * LL * DD; }

  // XCD-locality swizzle (bijective): the 8 p-tiles of one batch share x%8.
  const int x = blockIdx.x;
  const int b = ((x & 7) << 2) | (x >> 6);
  const int p0 = ((x >> 3) & 7) * 128 + wv * 32;
  const int p = p0 + l32;  // this lane's p-column

  const f16* Fq_b = Fq + (size_t)b * LL * DD;
  const f16* Fk_b = Fk + (size_t)b * LL * DD;
  const f16* Vt_b = Vt + (size_t)b * DD * LL;

  // Q fragments (B-operand): n=p=l32, k=half*8+j, 16 k-steps of 16
  f16x8 qf[16];
  {
    const f16* qrow = Fq_b + (size_t)p * DD + half * 8;
#pragma unroll
    for (int s = 0; s < 16; ++s) qf[s] = *(const f16x8*)&qrow[s * 16];
  }

  float m_run = -1e30f, l_run = 0.f;
  f32x16 o[8];
#pragma unroll
  for (int t = 0; t < 8; ++t) o[t] = (f32x16)(0.f);

  auto stage = [&](int buf, int q0) {
#pragma unroll
    for (int i = 0; i < 4; ++i) {
      int s = wv * 4 + i;
      async_copy16(Fk_b + (size_t)(q0 + l32) * DD + s * 16 + half * 8,
                   &Kf[buf][s][0]);
    }
#pragma unroll
    for (int i = 0; i < 4; ++i) {
      int v = wv * 4 + i;
      int t = v >> 1, h = v & 1;
      async_copy16(Vt_b + (size_t)(t * 32 + l32) * LL + q0 + h * 16 + half * 8,
                   &Vf[buf][v][0]);
    }
  };

  auto tile_compute = [&](int cur) {
    // S^T[q][p]: A = K frag (m=q), B = Q frag (n=p)
    f32x16 S = (f32x16)(0.f);
    __builtin_amdgcn_s_setprio(1);
#pragma unroll
    for (int s = 0; s < 16; ++s) {
      f16x8 kf = *(const f16x8*)&Kf[cur][s][lane * 8];  // conflict-free b128
      S = __builtin_amdgcn_mfma_f32_32x32x16_f16(kf, qf[s], S, 0, 0, 0);
    }
    __builtin_amdgcn_s_setprio(0);

    // in-lane softmax: lane holds 16 q-values of its p; merge with other half
    float mt = S[0];
#pragma unroll
    for (int r = 1; r < 16; ++r) mt = fmaxf(mt, S[r]);
    mt = fmaxf(mt, __shfl_xor(mt, 32, 64));

    // defer-max (T13): skip O-rescale while max growth <= 8
    const bool keep = __all((int)(mt - m_run <= 8.0f)) != 0;
    const float mn = keep ? m_run : fmaxf(m_run, mt);
    float pe[16];
    float ts = 0.f;
#pragma unroll
    for (int r = 0; r < 16; ++r) {
      pe[r] = __expf(S[r] - mn);
      ts += pe[r];
    }
    ts += __shfl_xor(ts, 32, 64);
    if (!keep) {
      const float alpha = __expf(m_run - mn);
      l_run *= alpha;
      m_run = mn;
#pragma unroll
      for (int t = 0; t < 8; ++t)
#pragma unroll
        for (int r = 0; r < 16; ++r) o[t][r] *= alpha;
    }
    l_run += ts;

    // build P^T B-frags: pack f16 pairs, exchange cross-half (4 shfl)
    u32 pw[8];
#pragma unroll
    for (int i = 0; i < 8; ++i) pw[i] = pack_pkrtz(pe[2 * i], pe[2 * i + 1]);
    u32 rc[4];
    {
      u32 s0 = half ? pw[0] : pw[2];
      u32 s1 = half ? pw[1] : pw[3];
      u32 s2 = half ? pw[4] : pw[6];
      u32 s3 = half ? pw[5] : pw[7];
      rc[0] = (u32)__shfl_xor((int)s0, 32, 64);
      rc[1] = (u32)__shfl_xor((int)s1, 32, 64);
      rc[2] = (u32)__shfl_xor((int)s2, 32, 64);
      rc[3] = (u32)__shfl_xor((int)s3, 32, 64);
    }
    f16x8 pf[2];
#pragma unroll
    for (int h = 0; h < 2; ++h) {
      u32 tmp[4];
      tmp[0] = half ? rc[2 * h] : pw[4 * h];
      tmp[1] = half ? rc[2 * h + 1] : pw[4 * h + 1];
      tmp[2] = half ? pw[4 * h + 2] : rc[2 * h];
      tmp[3] = half ? pw[4 * h + 3] : rc[2 * h + 1];
      __builtin_memcpy(&pf[h], tmp, 16);
    }

    // O^T += V^T P^T
    __builtin_amdgcn_s_setprio(1);
#pragma unroll
    for (int t = 0; t < 8; ++t) {
      f16x8 v0 = *(const f16x8*)&Vf[cur][t * 2][lane * 8];
      o[t] = __builtin_amdgcn_mfma_f32_32x32x16_f16(v0, pf[0], o[t], 0, 0, 0);
      f16x8 v1 = *(const f16x8*)&Vf[cur][t * 2 + 1][lane * 8];
      o[t] = __builtin_amdgcn_mfma_f32_32x32x16_f16(v1, pf[1], o[t], 0, 0, 0);
    }
    __builtin_amdgcn_s_setprio(0);
  };

  stage(0, 0);  // 8 loads in flight
  int cur = 0;
  for (int it = 0; it < 31; ++it) {
    stage(cur ^ 1, (it + 1) * 32);  // +8 in flight (safe: all waves passed
                                    // prev end-barrier, done reading buf^1)
    VMCNT(8);                        // own tile-it loads done; next stays in flight
    __builtin_amdgcn_sched_barrier(0);
    __builtin_amdgcn_s_barrier();    // everyone's tile-it DMA landed
    tile_compute(cur);
    __builtin_amdgcn_s_barrier();    // all reads of buf[cur] done
    cur ^= 1;
  }
  VMCNT(0);
  __builtin_amdgcn_sched_barrier(0);
  __builtin_amdgcn_s_barrier();
  tile_compute(cur);
  __syncthreads();  // all waves done with Kf before epilogue overlay

  // epilogue: per 32x32 chunk, transpose via per-wave LDS tile (stride 36:
  // write banksets (l32+C)%8 x8 lanes each, read ((l>>3)+(l&7))%8 x8 each --
  // perfectly balanced), then 8 rows x 128B contiguous global stores.
  const float inv = 1.f / l_run;
  float* Tw = (float*)&Kf[0][0][0] + wv * (32 * 36);
  float* Ob = O + (size_t)b * LL * DD;
#pragma unroll
  for (int t = 0; t < 8; ++t) {
#pragma unroll
    for (int g = 0; g < 4; ++g) {
      int C = 2 * g + half;  // chunk idx 0..7 <-> global col t*32 + C*4
      f32x4 v;
      v[0] = o[t][4 * g + 0] * inv;
      v[1] = o[t][4 * g + 1] * inv;
      v[2] = o[t][4 * g + 2] * inv;
      v[3] = o[t][4 * g + 3] * inv;
      *(f32x4*)&Tw[l32 * 36 + C * 4] = v;
    }
    LGKMCNT0;
#pragma unroll
    for (int pass = 0; pass < 4; ++pass) {
      int row = pass * 8 + (lane >> 3);
      int Cr = lane & 7;
      f32x4 v = *(const f32x4*)&Tw[row * 36 + Cr * 4];
      *(f32x4*)&Ob[(size_t)(p0 + row) * DD + t * 32 + Cr * 4] = v;
    }
    LGKMCNT0;  // reads of this t done before next t's writes
  }
}

// ---------------------------------------------------------------------------
extern "C" void kernel_launch(void* const* d_in, const int* in_sizes, int n_in,
                              void* d_out, int out_size, void* d_ws,
                              size_t ws_size, hipStream_t stream) {
  const float* premises = (const float*)d_in[0];    // [32,1024,256] fp32
  const float* hypotheses = (const float*)d_in[1];  // [32,1024,256] fp32
  const float* W = (const float*)d_in[2];           // [256,256] fp32
  float* out = (float*)d_out;

  const size_t MF = (size_t)BB * LL * DD;
  f16* Fp = (f16*)d_ws;   // 16 MiB each; ws = 64 MiB exactly
  f16* Fh = Fp + MF;
  f16* Vth = Fh + MF;     // hypotheses^T [B][D][L] f16
  f16* Vtp = Vth + MF;    // premises^T   [B][D][L] f16
  // Wt (131 KB) stashed in d_out tail: used only by proj, overwritten by flash
  f16* Wt = (f16*)((char*)d_out + (size_t)out_size * 4 - 256 * 256 * 2);

  // W^T -> f16
  transpose_to_f16<<<dim3(4, 4, 1), 256, 0, stream>>>(W, Wt, W, Wt, 256, 256, 1);
  // F = tanh(X @ W) f16 + fused X^T f16 emit; full-N per block (A read once)
  proj_mfma<<<dim3(512, 1, 2), 256, 0, stream>>>(premises, hypotheses, Wt, Fp,
                                                 Fh, Vtp, Vth);
  // betas (y=0) and alphas (y=1): 256 blocks/direction, 2 blocks/CU exactly
  flash_mfma<<<dim3(256, 2), 256, 0, stream>>>(Fp, Fh, Vth, Vtp, out);
}